// Round 2
// baseline (476.068 us; speedup 1.0000x reference)
//
#include <hip/hip_runtime.h>
#include <hip/hip_bf16.h>
#include <math.h>

// Problem constants (from reference setup_inputs)
#define BB   32
#define TT_  8192
#define QD   512
#define VD   256
#define DD   128
#define TINYF 1.17549435e-38f

// Tiling for the score kernel
#define TTILE 64   // t rows per block
#define CCH   32   // c-chunk

// Speculation window: scores computed eagerly for t < TSPEC; beyond that only
// if the exclusive cumprod has not underflowed to 0 (checked dynamically).
// E[log(1-p)] ~ -0.8/step -> cumsum ~ -205 at t=256, far below exp-underflow
// (-104), ~13 sigma margin. Fallback path keeps the general case correct.
#define TSPEC 256
#define TSPEC_TILES (TSPEC / TTILE)   // 4

// ---------------- Kernel A: scores for a t-range (q recomputed in-block) ----
// score[b][t] = sum_d attv[d]*tanh(q[b][d]+bv[d] + (value[b][t]@Wv)[d]) + sbias
// grid: (num_t_tiles, B); flags!=null -> early-exit when flags[b]==0.
__global__ __launch_bounds__(256) void k_score(
    const float* __restrict__ value, const float* __restrict__ query,
    const float* __restrict__ Wq, const float* __restrict__ bq,
    const float* __restrict__ Wv, const float* __restrict__ bv,
    const float* __restrict__ attv, const float* __restrict__ sbias,
    float* __restrict__ score, int t_tile_base, const int* __restrict__ flags) {
  int b = blockIdx.y;
  if (flags && flags[b] == 0) return;
  int tid = threadIdx.x;

  // ---- recompute q[b][:] + bq + bv into LDS (cheap: 256 FMA/thread) ----
  __shared__ float qrow[QD];
  __shared__ float qpart[2][DD];
  __shared__ float qsh[DD];
  qrow[tid]       = query[b * QD + tid];
  qrow[tid + 256] = query[b * QD + tid + 256];
  __syncthreads();
  {
    int h = tid >> 7, d = tid & 127;
    const float* wq = Wq + (size_t)(h * 256) * DD + d;
    const float* qr = qrow + h * 256;
    float acc = 0.f;
    #pragma unroll 8
    for (int c = 0; c < 256; ++c) acc = fmaf(qr[c], wq[(size_t)c * DD], acc);
    qpart[h][d] = acc;
  }
  __syncthreads();
  if (tid < DD) qsh[tid] = qpart[0][tid] + qpart[1][tid] + bq[tid] + bv[tid];
  __syncthreads();

  // ---- register-tiled GEMM: (value tile) @ Wv ----
  int t0 = (t_tile_base + blockIdx.x) * TTILE;
  int dq = tid & 31;   // d-group of 4: d = dq*4..dq*4+3
  int tq = tid >> 5;   // t-group of 8

  __shared__ float WvL[CCH * DD];        // 16 KB
  __shared__ float valT[CCH * 68];       // transposed value tile, stride 68

  float acc[8][4];
  #pragma unroll
  for (int i = 0; i < 8; ++i)
    #pragma unroll
    for (int j = 0; j < 4; ++j) acc[i][j] = 0.f;

  const float* vbase = value + ((size_t)b * TT_ + t0) * VD;

  for (int c0 = 0; c0 < VD; c0 += CCH) {
    const float4* wsrc = (const float4*)(Wv + (size_t)c0 * DD);
    float4* wdst = (float4*)WvL;
    #pragma unroll
    for (int k = 0; k < 4; ++k) wdst[tid + 256 * k] = wsrc[tid + 256 * k];
    #pragma unroll
    for (int k = 0; k < 2; ++k) {
      int id = tid * 2 + k;            // 0..511
      int tt = id >> 3;                // 0..63
      int c4 = id & 7;
      float4 vv = *(const float4*)(vbase + (size_t)tt * VD + c0 + c4 * 4);
      int cr = c4 * 4;
      valT[(cr + 0) * 68 + tt] = vv.x;
      valT[(cr + 1) * 68 + tt] = vv.y;
      valT[(cr + 2) * 68 + tt] = vv.z;
      valT[(cr + 3) * 68 + tt] = vv.w;
    }
    __syncthreads();
    #pragma unroll 4
    for (int cc = 0; cc < CCH; ++cc) {
      const float4 wv  = *(const float4*)(&WvL[cc * DD + dq * 4]);
      const float4 va0 = *(const float4*)(&valT[cc * 68 + tq * 8]);
      const float4 va1 = *(const float4*)(&valT[cc * 68 + tq * 8 + 4]);
      float va[8] = {va0.x, va0.y, va0.z, va0.w, va1.x, va1.y, va1.z, va1.w};
      #pragma unroll
      for (int i = 0; i < 8; ++i) {
        acc[i][0] = fmaf(va[i], wv.x, acc[i][0]);
        acc[i][1] = fmaf(va[i], wv.y, acc[i][1]);
        acc[i][2] = fmaf(va[i], wv.z, acc[i][2]);
        acc[i][3] = fmaf(va[i], wv.w, acc[i][3]);
      }
    }
    __syncthreads();
  }

  // epilogue: tanh + attv dot + cross-lane reduce over the 32 dq lanes
  float sb = sbias[0];
  float qd[4], av[4];
  #pragma unroll
  for (int j = 0; j < 4; ++j) {
    int d = dq * 4 + j;
    qd[j] = qsh[d];
    av[j] = attv[d];
  }
  #pragma unroll
  for (int i = 0; i < 8; ++i) {
    float s = 0.f;
    #pragma unroll
    for (int j = 0; j < 4; ++j) {
      float x = qd[j] + acc[i][j];
      s += av[j] * tanhf(x);
    }
    #pragma unroll
    for (int m = 16; m >= 1; m >>= 1) s += __shfl_xor(s, m, 64);
    if (dq == 0) score[(size_t)b * TT_ + t0 + tq * 8 + i] = s + sb;
  }
}

// ---------------- Kernel B: fused scan(window) + zero-tail + u + context ----
__global__ __launch_bounds__(256) void k_scan0_uctx(
    const float* __restrict__ score, const float* __restrict__ prev,
    const float* __restrict__ value, const float* __restrict__ Wv,
    const float* __restrict__ bv,
    float* __restrict__ align_out, float* __restrict__ ctx,
    float* __restrict__ suma, float* __restrict__ carryL,
    float* __restrict__ carryD, int* __restrict__ flags) {
  int b = blockIdx.x, tid = threadIdx.x;
  int lane = tid & 63, w = tid >> 6;
  __shared__ float wsA[4], wsB[4], wsS[4];
  __shared__ float aL[256];
  __shared__ float uL[256];
  const size_t base = (size_t)b * TT_;

  float s = score[base + tid];
  float p  = 1.f / (1.f + expf(-s));      // sigmoid
  float om = 1.f / (1.f + expf(s));       // 1-p without cancellation
  float l = logf(fmaxf(om, TINYF));       // log(clip(1-p, TINY, 1))

  // inclusive block scan of l
  float inc = l;
  #pragma unroll
  for (int o = 1; o < 64; o <<= 1) {
    float n = __shfl_up(inc, o, 64);
    if (lane >= o) inc += n;
  }
  if (lane == 63) wsA[w] = inc;
  __syncthreads();
  float off = 0.f;
  #pragma unroll
  for (int j = 0; j < 4; ++j) if (j < w) off += wsA[j];
  float totA = wsA[0] + wsA[1] + wsA[2] + wsA[3];
  float cums = off + inc;
  float cp = expf(cums - l);              // exclusive cumprod of (1-p)
  float den = prev[base + tid] / fminf(fmaxf(cp, 1e-10f), 1.f);

  // inclusive block scan of den
  float inc2 = den;
  #pragma unroll
  for (int o = 1; o < 64; o <<= 1) {
    float n = __shfl_up(inc2, o, 64);
    if (lane >= o) inc2 += n;
  }
  if (lane == 63) wsB[w] = inc2;
  __syncthreads();
  float off2 = 0.f;
  #pragma unroll
  for (int j = 0; j < 4; ++j) if (j < w) off2 += wsB[j];
  float totB = wsB[0] + wsB[1] + wsB[2] + wsB[3];

  float a = p * cp * (off2 + inc2);
  align_out[base + tid] = a;
  aL[tid] = a;

  // block-reduce sum(a)
  float sa = a;
  #pragma unroll
  for (int o = 32; o >= 1; o >>= 1) sa += __shfl_xor(sa, o, 64);
  if (lane == 0) wsS[w] = sa;
  __syncthreads();
  float stot = wsS[0] + wsS[1] + wsS[2] + wsS[3];

  bool done = (expf(totA) == 0.f);  // cp==0 for ALL later t -> alignment 0
  if (!done) {
    if (tid == 0) { flags[b] = 1; suma[b] = stot; carryL[b] = totA; carryD[b] = totB; }
    return;  // fallback kernels finish this b
  }
  if (tid == 0) { flags[b] = 0; suma[b] = stot; }

  // zero-fill alignment tail
  float4 z = make_float4(0.f, 0.f, 0.f, 0.f);
  float4* dst = (float4*)(align_out + base + TSPEC);
  for (int i = tid; i < (TT_ - TSPEC) / 4; i += 256) dst[i] = z;

  // u[c] = sum_t aL[t] * value[b][t][c]
  const float* vp = value + base * VD + tid;
  float acc = 0.f;
  #pragma unroll 8
  for (int t = 0; t < TSPEC; ++t) acc = fmaf(aL[t], vp[(size_t)t * VD], acc);
  uL[tid] = acc;
  __syncthreads();

  // ctx[d] = sum_c u[c]*Wv[c][d] + stot*bv[d]
  if (tid < DD) {
    float c = stot * bv[tid];
    #pragma unroll 8
    for (int cc = 0; cc < VD; ++cc) c = fmaf(uL[cc], Wv[cc * DD + tid], c);
    ctx[b * DD + tid] = c;
  }
}

// ---------------- Kernel D: scan continuation (fallback only) ----------------
__global__ __launch_bounds__(256) void k_scan1(
    const float* __restrict__ score, const float* __restrict__ prev,
    float* __restrict__ align_out, float* __restrict__ suma,
    const float* __restrict__ carryL, const float* __restrict__ carryD,
    const int* __restrict__ flags) {
  int b = blockIdx.x, tid = threadIdx.x;
  if (flags[b] == 0) return;
  int lane = tid & 63, w = tid >> 6;
  __shared__ float wsA[4], wsB[4];
  float cL = carryL[b], cD = carryD[b], sacc = suma[b];
  const size_t base = (size_t)b * TT_;
  const int chunk0 = TSPEC / 256, nchunks = TT_ / 256 - TSPEC / 256;

  for (int ch = 0; ch < nchunks; ++ch) {
    int t = (chunk0 + ch) * 256 + tid;
    float s = score[base + t];
    float p  = 1.f / (1.f + expf(-s));
    float om = 1.f / (1.f + expf(s));
    float l = logf(fmaxf(om, TINYF));

    float inc = l;
    #pragma unroll
    for (int o = 1; o < 64; o <<= 1) {
      float n = __shfl_up(inc, o, 64);
      if (lane >= o) inc += n;
    }
    if (lane == 63) wsA[w] = inc;
    __syncthreads();
    float off = 0.f;
    #pragma unroll
    for (int j = 0; j < 4; ++j) if (j < w) off += wsA[j];
    float totA = wsA[0] + wsA[1] + wsA[2] + wsA[3];
    float cums = cL + off + inc;
    float cp = expf(cums - l);
    float den = prev[base + t] / fminf(fmaxf(cp, 1e-10f), 1.f);

    float inc2 = den;
    #pragma unroll
    for (int o = 1; o < 64; o <<= 1) {
      float n = __shfl_up(inc2, o, 64);
      if (lane >= o) inc2 += n;
    }
    if (lane == 63) wsB[w] = inc2;
    __syncthreads();
    float off2 = 0.f;
    #pragma unroll
    for (int j = 0; j < 4; ++j) if (j < w) off2 += wsB[j];
    float totB = wsB[0] + wsB[1] + wsB[2] + wsB[3];

    float a = p * cp * (cD + off2 + inc2);
    align_out[base + t] = a;
    sacc += a;
    cL += totA; cD += totB;
    __syncthreads();
  }

  #pragma unroll
  for (int o = 32; o >= 1; o >>= 1) sacc += __shfl_xor(sacc, o, 64);
  if (lane == 0) wsA[w] = sacc;
  __syncthreads();
  if (tid == 0) suma[b] = wsA[0] + wsA[1] + wsA[2] + wsA[3];
}

// ---------------- Kernel E: u + context for fallback b ----------------
__global__ __launch_bounds__(256) void k_uctx_fb(
    const float* __restrict__ value, const float* __restrict__ align,
    const float* __restrict__ Wv, const float* __restrict__ bv,
    const float* __restrict__ suma, float* __restrict__ ctx,
    const int* __restrict__ flags) {
  int b = blockIdx.x, tid = threadIdx.x;
  if (flags[b] == 0) return;
  __shared__ float aL[256];
  __shared__ float uL[256];
  __shared__ int any;
  const size_t base = (size_t)b * TT_;
  float acc = 0.f;
  for (int ch = 0; ch < TT_ / 256; ++ch) {
    if (tid == 0) any = 0;
    __syncthreads();
    float a = align[base + ch * 256 + tid];
    aL[tid] = a;
    if (a != 0.f) any = 1;  // benign same-value race
    __syncthreads();
    if (any) {
      const float* vp = value + (base + (size_t)ch * 256) * VD + tid;
      #pragma unroll 8
      for (int t = 0; t < 256; ++t) acc = fmaf(aL[t], vp[(size_t)t * VD], acc);
    }
    __syncthreads();
  }
  uL[tid] = acc;
  __syncthreads();
  if (tid < DD) {
    float c = suma[b] * bv[tid];
    #pragma unroll 8
    for (int cc = 0; cc < VD; ++cc) c = fmaf(uL[cc], Wv[cc * DD + tid], c);
    ctx[b * DD + tid] = c;
  }
}

extern "C" void kernel_launch(void* const* d_in, const int* in_sizes, int n_in,
                              void* d_out, int out_size, void* d_ws, size_t ws_size,
                              hipStream_t stream) {
  const float* query = (const float*)d_in[0];
  const float* value = (const float*)d_in[1];
  const float* prev  = (const float*)d_in[2];
  const float* Wq    = (const float*)d_in[3];
  const float* bq    = (const float*)d_in[4];
  const float* Wv    = (const float*)d_in[5];
  const float* bv    = (const float*)d_in[6];
  const float* attv  = (const float*)d_in[7];
  const float* sbias = (const float*)d_in[8];

  float* ctx_out   = (float*)d_out;                 // [32][128]
  float* align_out = (float*)d_out + BB * DD;       // [32][8192]

  float* ws = (float*)d_ws;
  float* score  = ws;                  // 262144
  float* suma   = ws + 262144;         // 32
  float* carryL = ws + 262176;         // 32
  float* carryD = ws + 262208;         // 32
  int*   flags  = (int*)(ws + 262240); // 32

  // speculative scores for t < TSPEC
  k_score<<<dim3(TSPEC_TILES, BB), 256, 0, stream>>>(
      value, query, Wq, bq, Wv, bv, attv, sbias, score, 0, nullptr);

  // fused scan + zero-tail + u + ctx (fast path completes everything here)
  k_scan0_uctx<<<BB, 256, 0, stream>>>(score, prev, value, Wv, bv,
                                       align_out, ctx_out, suma,
                                       carryL, carryD, flags);

  // fallback: scores for t >= TSPEC (per-b early-exit when flags[b]==0)
  k_score<<<dim3(TT_ / TTILE - TSPEC_TILES, BB), 256, 0, stream>>>(
      value, query, Wq, bq, Wv, bv, attv, sbias, score, TSPEC_TILES, flags);

  // fallback: scan continuation
  k_scan1<<<BB, 256, 0, stream>>>(score, prev, align_out, suma,
                                  carryL, carryD, flags);

  // fallback: u + ctx for flagged b
  k_uctx_fb<<<BB, 256, 0, stream>>>(value, align_out, Wv, bv, suma,
                                    ctx_out, flags);
}